// Round 1
// 777.156 us; speedup vs baseline: 1.6707x; 1.6707x over previous
//
#include <hip/hip_runtime.h>
#include <hip/hip_fp16.h>

typedef _Float16 half8 __attribute__((ext_vector_type(8)));
typedef _Float16 half4 __attribute__((ext_vector_type(4)));
typedef float floatx4 __attribute__((ext_vector_type(4)));
typedef float fvec4 __attribute__((ext_vector_type(4)));

#define SS 50
#define HH 256
#define APAD 264                 // LDS row stride in halfs (528 B)
#define CABUF (16 * APAD)        // 4224 halfs per staging buffer
#define WHALF (768 * 256)        // halfs per weight matrix

__device__ __forceinline__ float sigm(float x) { return 1.f / (1.f + __expf(-x)); }
__device__ __forceinline__ float tanh_f(float x) {
    float ap = fabsf(x);
    float e2 = __expf(-2.f * ap);
    float th = (1.f - e2) / (1.f + e2);
    return (x < 0.f) ? -th : th;
}

// ---- phase 0: convert W_ih / W_hh fp32 -> fp16 into workspace ----
__global__ void cvt_w(const float* __restrict__ wih,
                      const float* __restrict__ whh,
                      _Float16* __restrict__ ws) {
    int idx = (blockIdx.x * 256 + threadIdx.x) * 4;
    const float* src = (idx < WHALF) ? (wih + idx) : (whh + (idx - WHALF));
    fvec4 v = *(const fvec4*)src;
    half4 h;
    h[0] = (_Float16)v.x; h[1] = (_Float16)v.y;
    h[2] = (_Float16)v.z; h[3] = (_Float16)v.w;
    *(half4*)(ws + idx) = h;
}

// ---- persistent fused kernel ----
// Dynamic LDS layout (halfs):
//   giL : Sc * 12288          (gi staging, thread-matched: tid*24, same thread
//                              produces in gi phase and consumes in scan phase)
//   cA  : 2 * CABUF           (C staging double buffer)
//   hA  : 2 * CABUF           (h f16 round-trip double buffer)
//   gL  : 16*SS floats        (G staged once per block, layout [s][row])
extern __shared__ _Float16 smem[];

__global__ __launch_bounds__(512, 2) void gru_all(
    const float* __restrict__ C, const float* __restrict__ G,
    const float* __restrict__ bih, const float* __restrict__ bhh,
    const _Float16* __restrict__ Wf, float* __restrict__ out, int Sc)
{
    _Float16* giL = smem;
    _Float16* cA  = smem + (size_t)Sc * 12288;
    _Float16* hAb = cA + 2 * CABUF;
    float*    gL  = (float*)(hAb + 2 * CABUF);

    const int tid  = threadIdx.x;
    const int w    = tid >> 6;
    const int lane = tid & 63;
    const int q    = lane >> 4;
    const int c    = lane & 15;
    const int rb   = blockIdx.x * 16;

    const _Float16* Wih = Wf;
    const _Float16* Whh = Wf + WHALF;

    // biases: bi (+ bh for r,z gates) folded into gi at store time; bh_n separate
    float bsum[6], bhn[2];
#pragma unroll
    for (int t2 = 0; t2 < 6; ++t2) {
        int g = t2 >> 1, t = t2 & 1;
        int n = g * 256 + w * 32 + t * 16 + c;
        bsum[t2] = bih[n] + (g < 2 ? bhh[n] : 0.f);
    }
#pragma unroll
    for (int t = 0; t < 2; ++t) bhn[t] = bhh[512 + w * 32 + t * 16 + c];

    float hreg[2][4];
#pragma unroll
    for (int t = 0; t < 2; ++t)
#pragma unroll
        for (int r = 0; r < 4; ++r) hreg[t][r] = 0.f;

    // init: zero h buffer 0, stage all G for this block's 16 rows
    for (int i = tid; i < CABUF; i += 512) hAb[i] = (_Float16)0.f;
    for (int i = tid; i < 16 * SS; i += 512)
        gL[i] = G[(size_t)(rb + (i & 15)) * SS + (i >> 4)];

    const int m_st = tid & 15;
    const int chk  = tid >> 4;             // 0..31, 8 floats each
    const float* crow = C + (size_t)(rb + m_st) * (SS * HH) + chk * 8;

    half8 wf[6][8];                        // 192 VGPRs of weight fragments (PINNED)
    int hp = 0;
    const int nch = (SS + Sc - 1) / Sc;

    for (int cc = 0; cc < nch; ++cc) {
        const int s0  = cc * Sc;
        const int Scc = (Sc < SS - s0) ? Sc : (SS - s0);

        // ======== gi phase: W_ih resident ========
#pragma unroll
        for (int t2 = 0; t2 < 6; ++t2) {
            const _Float16* base = Wih +
                (size_t)(((t2 >> 1) * 256 + w * 32 + (t2 & 1) * 16) + c) * HH + q * 8;
#pragma unroll
            for (int kt = 0; kt < 8; ++kt) wf[t2][kt] = *(const half8*)(base + kt * 32);
        }
        // pin: compiler must keep these 192 VGPRs live, cannot re-sink the loads
#pragma unroll
        for (int t2 = 0; t2 < 6; ++t2)
#pragma unroll
            for (int kt = 0; kt < 8; ++kt)
                asm volatile("" : "+v"(wf[t2][kt]));

        fvec4 cf0 = __builtin_nontemporal_load((const fvec4*)(crow + (size_t)s0 * HH));
        fvec4 cf1 = __builtin_nontemporal_load((const fvec4*)(crow + (size_t)s0 * HH + 4));

        for (int sc = 0; sc < Scc; ++sc) {
            const int s = s0 + sc;
            {
                half8 hv;
                hv[0] = (_Float16)cf0.x; hv[1] = (_Float16)cf0.y;
                hv[2] = (_Float16)cf0.z; hv[3] = (_Float16)cf0.w;
                hv[4] = (_Float16)cf1.x; hv[5] = (_Float16)cf1.y;
                hv[6] = (_Float16)cf1.z; hv[7] = (_Float16)cf1.w;
                *(half8*)&cA[(sc & 1) * CABUF + m_st * APAD + chk * 8] = hv;
            }
            __syncthreads();
            if (sc + 1 < Scc) {
                cf0 = __builtin_nontemporal_load((const fvec4*)(crow + (size_t)(s + 1) * HH));
                cf1 = __builtin_nontemporal_load((const fvec4*)(crow + (size_t)(s + 1) * HH + 4));
            }
            floatx4 acc[6];
#pragma unroll
            for (int t2 = 0; t2 < 6; ++t2) acc[t2] = (floatx4){0.f, 0.f, 0.f, 0.f};
#pragma unroll
            for (int kt = 0; kt < 8; ++kt) {
                half8 a = *(const half8*)&cA[(sc & 1) * CABUF + c * APAD + kt * 32 + q * 8];
#pragma unroll
                for (int t2 = 0; t2 < 6; ++t2)
                    acc[t2] = __builtin_amdgcn_mfma_f32_16x16x32_f16(a, wf[t2][kt], acc[t2], 0, 0, 0);
            }
            // gi (+biases) -> LDS, thread-matched layout: 24 halfs = 48 B per thread
            half8 o[3];
#pragma unroll
            for (int t2 = 0; t2 < 6; ++t2)
#pragma unroll
                for (int r = 0; r < 4; ++r) {
                    int idx = t2 * 4 + r;
                    o[idx >> 3][idx & 7] = (_Float16)(acc[t2][r] + bsum[t2]);
                }
            _Float16* gp = giL + (size_t)sc * 12288 + tid * 24;
            *(half8*)gp        = o[0];
            *(half8*)(gp + 8)  = o[1];
            *(half8*)(gp + 16) = o[2];
        }

        // ======== scan phase: W_hh resident ========
#pragma unroll
        for (int t2 = 0; t2 < 6; ++t2) {
            const _Float16* base = Whh +
                (size_t)(((t2 >> 1) * 256 + w * 32 + (t2 & 1) * 16) + c) * HH + q * 8;
#pragma unroll
            for (int kt = 0; kt < 8; ++kt) wf[t2][kt] = *(const half8*)(base + kt * 32);
        }
#pragma unroll
        for (int t2 = 0; t2 < 6; ++t2)
#pragma unroll
            for (int kt = 0; kt < 8; ++kt)
                asm volatile("" : "+v"(wf[t2][kt]));

        for (int sc = 0; sc < Scc; ++sc) {
            const int s = s0 + sc;
            __syncthreads();   // hA[hp] ready
            // gi read-back: own-thread LDS data, no extra barrier needed
            const _Float16* gp = giL + (size_t)sc * 12288 + tid * 24;
            half8 g0 = *(const half8*)gp;
            half8 g1 = *(const half8*)(gp + 8);
            half8 g2 = *(const half8*)(gp + 16);
            float gv[4];
#pragma unroll
            for (int r = 0; r < 4; ++r) gv[r] = gL[s * 16 + q * 4 + r];

            floatx4 acch[6];
#pragma unroll
            for (int t2 = 0; t2 < 6; ++t2) acch[t2] = (floatx4){0.f, 0.f, 0.f, 0.f};
#pragma unroll
            for (int kt = 0; kt < 8; ++kt) {
                half8 a = *(const half8*)&hAb[hp * CABUF + c * APAD + kt * 32 + q * 8];
#pragma unroll
                for (int t2 = 0; t2 < 6; ++t2)
                    acch[t2] = __builtin_amdgcn_mfma_f32_16x16x32_f16(a, wf[t2][kt], acch[t2], 0, 0, 0);
            }

            _Float16* hw = hAb + (hp ^ 1) * CABUF;
#pragma unroll
            for (int t = 0; t < 2; ++t)
#pragma unroll
                for (int r = 0; r < 4; ++r) {
                    float i_r = (float)g0[t * 4 + r];
                    float i_z = (float)g1[t * 4 + r];
                    float i_n = (float)g2[t * 4 + r];
                    float h_r = acch[0 * 2 + t][r];
                    float h_z = acch[1 * 2 + t][r];
                    float h_n = acch[2 * 2 + t][r] + bhn[t];
                    float rg = sigm(i_r + h_r);
                    float zg = sigm(i_z + h_z);
                    float ng = tanh_f(i_n + rg * h_n);
                    float hold = hreg[t][r];
                    float hnew = (1.f - zg) * ng + zg * hold;
                    float gg = gv[r];
                    float hout = gg * hnew + (1.f - gg) * hold;
                    hreg[t][r] = hout;
                    hw[(q * 4 + r) * APAD + w * 32 + t * 16 + c] = (_Float16)hout;
                }
            hp ^= 1;
        }
    }

#pragma unroll
    for (int t = 0; t < 2; ++t)
#pragma unroll
        for (int r = 0; r < 4; ++r)
            out[(size_t)(rb + q * 4 + r) * HH + w * 32 + t * 16 + c] = hreg[t][r];
}

extern "C" void kernel_launch(void* const* d_in, const int* in_sizes, int n_in,
                              void* d_out, int out_size, void* d_ws, size_t ws_size,
                              hipStream_t stream) {
    const float* C   = (const float*)d_in[0];
    const float* G   = (const float*)d_in[1];
    const float* Wih = (const float*)d_in[2];
    const float* Whh = (const float*)d_in[3];
    const float* bih = (const float*)d_in[4];
    const float* bhh = (const float*)d_in[5];
    _Float16* wsh = (_Float16*)d_ws;            // f16 weights: 786432 bytes

    // One-time: raise dynamic LDS limit for the Sc=5 config (159,872 B).
    // gfx950 supports 160 KiB/workgroup. Fallback Sc=1 (61,568 B) if refused.
    static int Sc_cached = 0;
    if (Sc_cached == 0) {
        const int shm5 = 5 * 24576 + 4 * CABUF * 2 + 16 * SS * 4;   // 159872
        hipError_t e = hipFuncSetAttribute((const void*)gru_all,
                          hipFuncAttributeMaxDynamicSharedMemorySize, shm5);
        Sc_cached = (e == hipSuccess) ? 5 : 1;
    }
    const int Sc = Sc_cached;
    const size_t shmem = (size_t)Sc * 24576 + 4 * CABUF * 2 + 16 * SS * 4;

    cvt_w<<<384, 256, 0, stream>>>(Wih, Whh, wsh);
    gru_all<<<256, 512, shmem, stream>>>(C, G, bih, bhh, wsh, (float*)d_out, Sc);
}